// Round 1
// baseline (840.686 us; speedup 1.0000x reference)
//
#include <hip/hip_runtime.h>

#define NN   100000
#define NE   1600000
#define NB_SCAN 98          // ceil(NN/1024)

// ============================ CSR build ============================

__global__ __launch_bounds__(256) void k_zero(int* __restrict__ p, int n) {
  int i = blockIdx.x * 256 + threadIdx.x;
  if (i < n) p[i] = 0;
}

__global__ __launch_bounds__(256) void k_count(const int* __restrict__ dst, int* __restrict__ deg) {
  int e = blockIdx.x * 256 + threadIdx.x;
  if (e < NE) atomicAdd(&deg[dst[e]], 1);
}

// block-local exclusive scan: 1024 elements / block (256 thr x 4)
__global__ __launch_bounds__(256) void k_scan1(const int* __restrict__ deg, int* __restrict__ offs,
                                               int* __restrict__ bsum) {
  __shared__ int sh[256];
  int t = threadIdx.x;
  int base = blockIdx.x * 1024 + t * 4;
  int v0 = (base + 0 < NN) ? deg[base + 0] : 0;
  int v1 = (base + 1 < NN) ? deg[base + 1] : 0;
  int v2 = (base + 2 < NN) ? deg[base + 2] : 0;
  int v3 = (base + 3 < NN) ? deg[base + 3] : 0;
  int s = v0 + v1 + v2 + v3;
  int x = s;
  sh[t] = x;
  for (int off = 1; off < 256; off <<= 1) {
    __syncthreads();
    int y = (t >= off) ? sh[t - off] : 0;
    __syncthreads();
    x += y;
    sh[t] = x;
  }
  int ex = x - s;
  if (base + 0 < NN) offs[base + 0] = ex;
  if (base + 1 < NN) offs[base + 1] = ex + v0;
  if (base + 2 < NN) offs[base + 2] = ex + v0 + v1;
  if (base + 3 < NN) offs[base + 3] = ex + v0 + v1 + v2;
  if (t == 255) bsum[blockIdx.x] = x;
}

__global__ __launch_bounds__(256) void k_scan2(int* __restrict__ bsum, int nb) {
  __shared__ int sh[256];
  int t = threadIdx.x;
  int v = (t < nb) ? bsum[t] : 0;
  int x = v;
  sh[t] = x;
  for (int off = 1; off < 256; off <<= 1) {
    __syncthreads();
    int y = (t >= off) ? sh[t - off] : 0;
    __syncthreads();
    x += y;
    sh[t] = x;
  }
  if (t < nb) bsum[t] = x - v;  // exclusive
}

__global__ __launch_bounds__(256) void k_scan3(int* __restrict__ offs, const int* __restrict__ bsum,
                                               int* __restrict__ cursor) {
  int i = blockIdx.x * 256 + threadIdx.x;
  if (i < NN) {
    offs[i] += bsum[i >> 10];
    cursor[i] = 0;
  }
  if (i == 0) offs[NN] = NE;
}

__global__ __launch_bounds__(256) void k_scatter(const int* __restrict__ src, const int* __restrict__ dst,
                                                 const int* __restrict__ offs, int* __restrict__ cursor,
                                                 int* __restrict__ adj) {
  int e = blockIdx.x * 256 + threadIdx.x;
  if (e < NE) {
    int d = dst[e];
    int pos = atomicAdd(&cursor[d], 1);
    adj[offs[d] + pos] = src[e];
  }
}

// ============================ GEMM + attention logits ============================
// H = X @ W  (NN x 128 = NN x 128 @ 128 x 128), plus a_src/a_dst = einsum(h, att)
// block tile: 64 rows x 128 cols; 256 threads; thread tile 8 rows x 4 cols; K-tiles of 32.
__global__ __launch_bounds__(256) void k_gemm_att(const float* __restrict__ X, const float* __restrict__ W,
                                                  const float* __restrict__ atts, const float* __restrict__ attd,
                                                  float* __restrict__ H, float* __restrict__ asrc,
                                                  float* __restrict__ adst) {
  __shared__ __align__(16) float Wt[32 * 128];   // [kk][col]
  __shared__ __align__(16) float Xt[32 * 72];    // [kk][row], stride 72
  int t = threadIdx.x;
  int rb = blockIdx.x * 64;
  int cg = (t & 31) * 4;        // col base (4 cols)
  int rg = (t >> 5) * 8;        // row base within tile (8 rows)
  float acc[8][4];
#pragma unroll
  for (int r = 0; r < 8; r++)
#pragma unroll
    for (int c = 0; c < 4; c++) acc[r][c] = 0.f;

  for (int k0 = 0; k0 < 128; k0 += 32) {
    __syncthreads();
    // W tile: 32x128 floats = 1024 float4
    {
      const float4* Wg = (const float4*)(W + k0 * 128);
      float4* Wl = (float4*)Wt;
#pragma unroll
      for (int i = 0; i < 4; i++) Wl[i * 256 + t] = Wg[i * 256 + t];
    }
    // X tile: 64 rows x 32 k, transposed into Xt[kk][row]
#pragma unroll
    for (int i = 0; i < 8; i++) {
      int lin = i * 256 + t;
      int row = lin >> 5;       // 0..63
      int kk = lin & 31;
      float v = (rb + row < NN) ? X[(rb + row) * 128 + k0 + kk] : 0.f;
      Xt[kk * 72 + row] = v;
    }
    __syncthreads();
#pragma unroll 8
    for (int kk = 0; kk < 32; kk++) {
      float4 w4 = *(const float4*)(Wt + kk * 128 + cg);
      float4 xa = *(const float4*)(Xt + kk * 72 + rg);
      float4 xb = *(const float4*)(Xt + kk * 72 + rg + 4);
      float xs[8] = {xa.x, xa.y, xa.z, xa.w, xb.x, xb.y, xb.z, xb.w};
#pragma unroll
      for (int r = 0; r < 8; r++) {
        acc[r][0] += xs[r] * w4.x;
        acc[r][1] += xs[r] * w4.y;
        acc[r][2] += xs[r] * w4.z;
        acc[r][3] += xs[r] * w4.w;
      }
    }
  }

  // store H
  int row0 = rb + rg;
#pragma unroll
  for (int r = 0; r < 8; r++) {
    if (row0 + r < NN) {
      float4 o = make_float4(acc[r][0], acc[r][1], acc[r][2], acc[r][3]);
      *(float4*)(H + (row0 + r) * 128 + cg) = o;
    }
  }

  // attention logits: a_src[n][h] = sum_c h[n][h*32+c]*atts[h][c]
  int head = cg >> 5;
  int cb = cg & 31;
  float s0 = atts[head * 32 + cb + 0], s1 = atts[head * 32 + cb + 1];
  float s2 = atts[head * 32 + cb + 2], s3 = atts[head * 32 + cb + 3];
  float d0 = attd[head * 32 + cb + 0], d1 = attd[head * 32 + cb + 1];
  float d2 = attd[head * 32 + cb + 2], d3 = attd[head * 32 + cb + 3];
  float ps[8], pd[8];
#pragma unroll
  for (int r = 0; r < 8; r++) {
    ps[r] = acc[r][0] * s0 + acc[r][1] * s1 + acc[r][2] * s2 + acc[r][3] * s3;
    pd[r] = acc[r][0] * d0 + acc[r][1] * d1 + acc[r][2] * d2 + acc[r][3] * d3;
  }
  // reduce across the 8 lanes (same head, cols) -- lane ids differ in bits 0..2
#pragma unroll
  for (int m = 1; m < 8; m <<= 1) {
#pragma unroll
    for (int r = 0; r < 8; r++) {
      ps[r] += __shfl_xor(ps[r], m, 64);
      pd[r] += __shfl_xor(pd[r], m, 64);
    }
  }
  int j = t & 7;
  float vs = ps[0], vd = pd[0];
#pragma unroll
  for (int r = 1; r < 8; r++) {
    if (j == r) { vs = ps[r]; vd = pd[r]; }
  }
  if (row0 + j < NN) {
    asrc[(row0 + j) * 4 + head] = vs;
    adst[(row0 + j) * 4 + head] = vd;
  }
}

// ============================ per-node gather aggregation ============================
// one 64-lane wave per destination node; lane owns 2 of the 128 channels.
// out[d] = relu( (sum_e w_e h[src_e] + w_self h[d]) / (sum w + w_self) + bias )
__global__ __launch_bounds__(256) void k_aggregate(const float* __restrict__ H, const int* __restrict__ offs,
                                                   const int* __restrict__ adj, const float* __restrict__ asrc,
                                                   const float* __restrict__ adst, const float* __restrict__ bias,
                                                   float* __restrict__ out) {
  int n = blockIdx.x * 4 + (threadIdx.x >> 6);
  if (n >= NN) return;
  int lane = threadIdx.x & 63;
  int head = lane >> 4;              // cols [2*lane, 2*lane+1] both in this head
  float ad = adst[n * 4 + head];
  float ax = 0.f, ay = 0.f, wsum = 0.f;
  int beg = offs[n], end = offs[n + 1];
  for (int i = beg; i < end; i++) {
    int s = adj[i];
    float e = asrc[s * 4 + head] + ad;
    e = (e > 0.f) ? e : 0.2f * e;
    float w = __expf(e);
    wsum += w;
    float2 hv = *(const float2*)(H + s * 128 + lane * 2);
    ax += w * hv.x;
    ay += w * hv.y;
  }
  // self loop
  {
    float e = asrc[n * 4 + head] + ad;
    e = (e > 0.f) ? e : 0.2f * e;
    float w = __expf(e);
    wsum += w;
    float2 hv = *(const float2*)(H + n * 128 + lane * 2);
    ax += w * hv.x;
    ay += w * hv.y;
  }
  float inv = 1.0f / (wsum + 1e-16f);
  float bx = bias[lane * 2], by = bias[lane * 2 + 1];
  float ox = ax * inv + bx;
  float oy = ay * inv + by;
  ox = fmaxf(ox, 0.f);
  oy = fmaxf(oy, 0.f);
  *(float2*)(out + n * 128 + lane * 2) = make_float2(ox, oy);
}

// ============================ classifier ============================
// out[n][c] = sum_k Hf[n][k] * Wc[k][c] + bc[c];  6 nodes / block (240 of 256 lanes active)
__global__ __launch_bounds__(256) void k_classifier(const float* __restrict__ Hf, const float* __restrict__ Wc,
                                                    const float* __restrict__ bc, float* __restrict__ out) {
  __shared__ float shW[128 * 40];
  __shared__ float shH[6 * 128];
  int t = threadIdx.x;
  for (int i = t; i < 128 * 40; i += 256) shW[i] = Wc[i];
  int nb = blockIdx.x * 6;
  for (int i = t; i < 6 * 128; i += 256) {
    int r = i >> 7, c = i & 127;
    shH[i] = (nb + r < NN) ? Hf[(nb + r) * 128 + c] : 0.f;
  }
  __syncthreads();
  if (t < 240) {
    int loc = t / 40;
    int c = t - loc * 40;
    int node = nb + loc;
    if (node < NN) {
      float acc = bc[c];
#pragma unroll 8
      for (int k = 0; k < 128; k++) acc += shH[loc * 128 + k] * shW[k * 40 + c];
      out[node * 40 + c] = acc;
    }
  }
}

// ============================ launch ============================

extern "C" void kernel_launch(void* const* d_in, const int* in_sizes, int n_in,
                              void* d_out, int out_size, void* d_ws, size_t ws_size,
                              hipStream_t stream) {
  const float* x   = (const float*)d_in[0];
  const int*   ei  = (const int*)d_in[1];
  const float* W1  = (const float*)d_in[2];
  const float* as1 = (const float*)d_in[3];
  const float* ad1 = (const float*)d_in[4];
  const float* b1  = (const float*)d_in[5];
  const float* W2  = (const float*)d_in[6];
  const float* as2 = (const float*)d_in[7];
  const float* ad2 = (const float*)d_in[8];
  const float* b2  = (const float*)d_in[9];
  const float* Wc  = (const float*)d_in[10];
  const float* bc  = (const float*)d_in[11];
  float* out = (float*)d_out;

  const int* esrc = ei;
  const int* edst = ei + NE;

  char* w = (char*)d_ws;
  auto alloc = [&](size_t bytes) {
    void* p = (void*)w;
    w += (bytes + 255) & ~(size_t)255;
    return p;
  };
  float* A    = (float*)alloc(sizeof(float) * (size_t)NN * 128);
  float* B    = (float*)alloc(sizeof(float) * (size_t)NN * 128);
  float* asrc = (float*)alloc(sizeof(float) * (size_t)NN * 4);
  float* adst = (float*)alloc(sizeof(float) * (size_t)NN * 4);
  int* deg    = (int*)alloc(sizeof(int) * NN);
  int* offs   = (int*)alloc(sizeof(int) * (NN + 1));
  int* cursor = (int*)alloc(sizeof(int) * NN);
  int* adj    = (int*)alloc(sizeof(int) * NE);
  int* bsum   = (int*)alloc(sizeof(int) * 256);

  // ---- CSR build (same graph both layers) ----
  k_zero<<<(NN + 255) / 256, 256, 0, stream>>>(deg, NN);
  k_count<<<(NE + 255) / 256, 256, 0, stream>>>(edst, deg);
  k_scan1<<<NB_SCAN, 256, 0, stream>>>(deg, offs, bsum);
  k_scan2<<<1, 256, 0, stream>>>(bsum, NB_SCAN);
  k_scan3<<<(NN + 255) / 256, 256, 0, stream>>>(offs, bsum, cursor);
  k_scatter<<<(NE + 255) / 256, 256, 0, stream>>>(esrc, edst, offs, cursor, adj);

  // ---- layer 1 ----
  k_gemm_att<<<(NN + 63) / 64, 256, 0, stream>>>(x, W1, as1, ad1, A, asrc, adst);
  k_aggregate<<<(NN + 3) / 4, 256, 0, stream>>>(A, offs, adj, asrc, adst, b1, B);

  // ---- layer 2 ----
  k_gemm_att<<<(NN + 63) / 64, 256, 0, stream>>>(B, W2, as2, ad2, A, asrc, adst);
  k_aggregate<<<(NN + 3) / 4, 256, 0, stream>>>(A, offs, adj, asrc, adst, b2, B);

  // ---- classifier ----
  k_classifier<<<(NN + 5) / 6, 256, 0, stream>>>(B, Wc, bc, out);
}

// Round 2
// 652.278 us; speedup vs baseline: 1.2888x; 1.2888x over previous
//
#include <hip/hip_runtime.h>

#define NN   100000
#define NE   1600000
#define NB_SCAN 98          // ceil(NN/1024)

typedef _Float16 half_t;
typedef __attribute__((ext_vector_type(4))) _Float16 f16x4;
typedef __attribute__((ext_vector_type(8))) _Float16 f16x8;
typedef __attribute__((ext_vector_type(4))) float    f32x4;

// ============================ CSR build ============================

__global__ __launch_bounds__(256) void k_zero(int* __restrict__ p, int n) {
  int i = blockIdx.x * 256 + threadIdx.x;
  if (i < n) p[i] = 0;
}

__global__ __launch_bounds__(256) void k_count(const int* __restrict__ dst, int* __restrict__ deg) {
  int e = blockIdx.x * 256 + threadIdx.x;
  if (e < NE) atomicAdd(&deg[dst[e]], 1);
}

__global__ __launch_bounds__(256) void k_scan1(const int* __restrict__ deg, int* __restrict__ offs,
                                               int* __restrict__ bsum) {
  __shared__ int sh[256];
  int t = threadIdx.x;
  int base = blockIdx.x * 1024 + t * 4;
  int v0 = (base + 0 < NN) ? deg[base + 0] : 0;
  int v1 = (base + 1 < NN) ? deg[base + 1] : 0;
  int v2 = (base + 2 < NN) ? deg[base + 2] : 0;
  int v3 = (base + 3 < NN) ? deg[base + 3] : 0;
  int s = v0 + v1 + v2 + v3;
  int x = s;
  sh[t] = x;
  for (int off = 1; off < 256; off <<= 1) {
    __syncthreads();
    int y = (t >= off) ? sh[t - off] : 0;
    __syncthreads();
    x += y;
    sh[t] = x;
  }
  int ex = x - s;
  if (base + 0 < NN) offs[base + 0] = ex;
  if (base + 1 < NN) offs[base + 1] = ex + v0;
  if (base + 2 < NN) offs[base + 2] = ex + v0 + v1;
  if (base + 3 < NN) offs[base + 3] = ex + v0 + v1 + v2;
  if (t == 255) bsum[blockIdx.x] = x;
}

__global__ __launch_bounds__(256) void k_scan2(int* __restrict__ bsum, int nb) {
  __shared__ int sh[256];
  int t = threadIdx.x;
  int v = (t < nb) ? bsum[t] : 0;
  int x = v;
  sh[t] = x;
  for (int off = 1; off < 256; off <<= 1) {
    __syncthreads();
    int y = (t >= off) ? sh[t - off] : 0;
    __syncthreads();
    x += y;
    sh[t] = x;
  }
  if (t < nb) bsum[t] = x - v;  // exclusive
}

__global__ __launch_bounds__(256) void k_scan3(int* __restrict__ offs, const int* __restrict__ bsum,
                                               int* __restrict__ cursor) {
  int i = blockIdx.x * 256 + threadIdx.x;
  if (i < NN) {
    offs[i] += bsum[i >> 10];
    cursor[i] = 0;
  }
  if (i == 0) offs[NN] = NE;
}

__global__ __launch_bounds__(256) void k_scatter(const int* __restrict__ src, const int* __restrict__ dst,
                                                 const int* __restrict__ offs, int* __restrict__ cursor,
                                                 int* __restrict__ adj) {
  int e = blockIdx.x * 256 + threadIdx.x;
  if (e < NE) {
    int d = dst[e];
    int pos = atomicAdd(&cursor[d], 1);
    adj[offs[d] + pos] = src[e];
  }
}

// ============================ MFMA GEMM + attention logits ============================
// H(fp16) = fp16(X) @ fp16(W); asrc/adst logits fp32 from the C-fragments.
// block: 256 thr = 4 waves; tile 128 rows x 128 cols; K-steps of 32.
// wave w -> rows [w*32, w*32+32): 2 row-tiles x 8 col-tiles of 16x16x32 mfma.
// A-frag: lane holds A[m=lane&15][k=quad*8+j]  (row-major [m][k] in LDS)
// B-frag: lane holds B[k=quad*8+j][n=lane&15]  (transposed [n][k] in LDS)
// C-frag: col=lane&15, row=quad*4+reg
__global__ __launch_bounds__(256) void k_gemm_att(const float* __restrict__ X, const float* __restrict__ W,
                                                  const float* __restrict__ atts, const float* __restrict__ attd,
                                                  half_t* __restrict__ H, float* __restrict__ asrc,
                                                  float* __restrict__ adst) {
  __shared__ __align__(16) half_t Xt[128 * 40];   // [row][k], stride 40 halves
  __shared__ __align__(16) half_t Wt[128 * 40];   // [n][k], stride 40 halves
  int t = threadIdx.x;
  int wave = t >> 6, lane = t & 63;
  int l15 = lane & 15, quad = lane >> 4;
  int rb = blockIdx.x * 128;

  f32x4 acc[2][8];
#pragma unroll
  for (int rt = 0; rt < 2; rt++)
#pragma unroll
    for (int ct = 0; ct < 8; ct++) acc[rt][ct] = (f32x4){0.f, 0.f, 0.f, 0.f};

  for (int k0 = 0; k0 < 128; k0 += 32) {
    __syncthreads();
    // stage X tile: 128 rows x 32 k (fp32 -> fp16)
#pragma unroll
    for (int i = 0; i < 4; i++) {
      int lin = i * 256 + t;
      int row = lin >> 3;
      int c4 = (lin & 7) * 4;
      float4 v = make_float4(0.f, 0.f, 0.f, 0.f);
      int gr = rb + row;
      if (gr < NN) v = *(const float4*)(X + (size_t)gr * 128 + k0 + c4);
      f16x4 hv;
      hv[0] = (half_t)v.x; hv[1] = (half_t)v.y; hv[2] = (half_t)v.z; hv[3] = (half_t)v.w;
      *(f16x4*)(Xt + row * 40 + c4) = hv;
    }
    // stage W^T tile: read W[k0+kr][n] coalesced, write Wt[n][kr]
#pragma unroll
    for (int i = 0; i < 4; i++) {
      int lin = i * 256 + t;
      int kr = lin >> 5;
      int n4 = (lin & 31) * 4;
      float4 v = *(const float4*)(W + (size_t)(k0 + kr) * 128 + n4);
      Wt[(n4 + 0) * 40 + kr] = (half_t)v.x;
      Wt[(n4 + 1) * 40 + kr] = (half_t)v.y;
      Wt[(n4 + 2) * 40 + kr] = (half_t)v.z;
      Wt[(n4 + 3) * 40 + kr] = (half_t)v.w;
    }
    __syncthreads();

    f16x8 a0 = *(const f16x8*)(Xt + (wave * 32 + l15) * 40 + quad * 8);
    f16x8 a1 = *(const f16x8*)(Xt + (wave * 32 + 16 + l15) * 40 + quad * 8);
#pragma unroll
    for (int ct = 0; ct < 8; ct++) {
      f16x8 b = *(const f16x8*)(Wt + (ct * 16 + l15) * 40 + quad * 8);
      acc[0][ct] = __builtin_amdgcn_mfma_f32_16x16x32_f16(a0, b, acc[0][ct], 0, 0, 0);
      acc[1][ct] = __builtin_amdgcn_mfma_f32_16x16x32_f16(a1, b, acc[1][ct], 0, 0, 0);
    }
  }

  // ---- store H as fp16 ----
#pragma unroll
  for (int rt = 0; rt < 2; rt++) {
    int rbase = rb + wave * 32 + rt * 16 + quad * 4;
#pragma unroll
    for (int reg = 0; reg < 4; reg++) {
      int row = rbase + reg;
      if (row < NN) {
#pragma unroll
        for (int ct = 0; ct < 8; ct++) {
          H[(size_t)row * 128 + ct * 16 + l15] = (half_t)acc[rt][ct][reg];
        }
      }
    }
  }

  // ---- attention logits ----
  // lane's col in col-tile ct is ct*16+l15; head h covers tiles {2h, 2h+1}.
  float s_lo[4], s_hi[4], d_lo[4], d_hi[4];
#pragma unroll
  for (int h = 0; h < 4; h++) {
    s_lo[h] = atts[h * 32 + l15];
    s_hi[h] = atts[h * 32 + 16 + l15];
    d_lo[h] = attd[h * 32 + l15];
    d_hi[h] = attd[h * 32 + 16 + l15];
  }
#pragma unroll
  for (int rt = 0; rt < 2; rt++) {
    float ps[4][4], pd[4][4];  // [reg][head], partial over this lane's col
#pragma unroll
    for (int reg = 0; reg < 4; reg++)
#pragma unroll
      for (int h = 0; h < 4; h++) {
        ps[reg][h] = acc[rt][2 * h][reg] * s_lo[h] + acc[rt][2 * h + 1][reg] * s_hi[h];
        pd[reg][h] = acc[rt][2 * h][reg] * d_lo[h] + acc[rt][2 * h + 1][reg] * d_hi[h];
      }
    // reduce over the 16 cols (lane bits 0..3)
#pragma unroll
    for (int m = 1; m < 16; m <<= 1) {
#pragma unroll
      for (int reg = 0; reg < 4; reg++)
#pragma unroll
        for (int h = 0; h < 4; h++) {
          ps[reg][h] += __shfl_xor(ps[reg][h], m, 64);
          pd[reg][h] += __shfl_xor(pd[reg][h], m, 64);
        }
    }
    // lane l15 = reg*4 + h writes (row=quad*4+reg, head=h)
    float vs = 0.f, vd = 0.f;
#pragma unroll
    for (int reg = 0; reg < 4; reg++)
#pragma unroll
      for (int h = 0; h < 4; h++) {
        if (l15 == reg * 4 + h) { vs = ps[reg][h]; vd = pd[reg][h]; }
      }
    int row = rb + wave * 32 + rt * 16 + quad * 4 + (l15 >> 2);
    int h = l15 & 3;
    if (row < NN) {
      asrc[row * 4 + h] = vs;
      adst[row * 4 + h] = vd;
    }
  }
}

// ============================ per-node gather aggregation ============================
// one 64-lane wave per destination node; 16 lanes x half8 cover one 128-ch row,
// so 4 edges are processed concurrently (groups g=0..3).
__global__ __launch_bounds__(256) void k_aggregate(const half_t* __restrict__ H, const int* __restrict__ offs,
                                                   const int* __restrict__ adj, const float* __restrict__ asrc,
                                                   const float* __restrict__ adst, const float* __restrict__ bias,
                                                   float* __restrict__ out) {
  int n = blockIdx.x * 4 + (threadIdx.x >> 6);
  if (n >= NN) return;
  int lane = threadIdx.x & 63;
  int l15 = lane & 15, g = lane >> 4;
  int head = l15 >> 2;                 // channels [l15*8, l15*8+8) all in this head
  float ad = adst[n * 4 + head];
  float acc[8] = {0.f, 0.f, 0.f, 0.f, 0.f, 0.f, 0.f, 0.f};
  float wsum = 0.f;
  int beg = offs[n], end = offs[n + 1];
  for (int i = beg + g; i < end; i += 4) {
    int s = adj[i];
    float e = asrc[s * 4 + head] + ad;
    e = (e > 0.f) ? e : 0.2f * e;
    float w = __expf(e);
    wsum += w;
    f16x8 hv = *(const f16x8*)(H + (size_t)s * 128 + l15 * 8);
#pragma unroll
    for (int j = 0; j < 8; j++) acc[j] += w * (float)hv[j];
  }
  if (g == 0) {  // self loop, counted once
    float e = asrc[n * 4 + head] + ad;
    e = (e > 0.f) ? e : 0.2f * e;
    float w = __expf(e);
    wsum += w;
    f16x8 hv = *(const f16x8*)(H + (size_t)n * 128 + l15 * 8);
#pragma unroll
    for (int j = 0; j < 8; j++) acc[j] += w * (float)hv[j];
  }
  // combine the 4 edge-groups
#pragma unroll
  for (int m = 16; m < 64; m <<= 1) {
    wsum += __shfl_xor(wsum, m, 64);
#pragma unroll
    for (int j = 0; j < 8; j++) acc[j] += __shfl_xor(acc[j], m, 64);
  }
  float inv = 1.0f / (wsum + 1e-16f);
  // lane writes channels l15*8 + g*2, +1 (full row covered by the wave)
  float o0 = acc[0], o1 = acc[1];
  if (g == 1) { o0 = acc[2]; o1 = acc[3]; }
  if (g == 2) { o0 = acc[4]; o1 = acc[5]; }
  if (g == 3) { o0 = acc[6]; o1 = acc[7]; }
  int ch = l15 * 8 + g * 2;
  o0 = o0 * inv + bias[ch];
  o1 = o1 * inv + bias[ch + 1];
  o0 = fmaxf(o0, 0.f);
  o1 = fmaxf(o1, 0.f);
  *(float2*)(out + (size_t)n * 128 + ch) = make_float2(o0, o1);
}

// ============================ classifier ============================
__global__ __launch_bounds__(256) void k_classifier(const float* __restrict__ Hf, const float* __restrict__ Wc,
                                                    const float* __restrict__ bc, float* __restrict__ out) {
  __shared__ float shW[128 * 40];
  __shared__ float shH[6 * 128];
  int t = threadIdx.x;
  for (int i = t; i < 128 * 40; i += 256) shW[i] = Wc[i];
  int nb = blockIdx.x * 6;
  for (int i = t; i < 6 * 128; i += 256) {
    int r = i >> 7, c = i & 127;
    shH[i] = (nb + r < NN) ? Hf[(size_t)(nb + r) * 128 + c] : 0.f;
  }
  __syncthreads();
  if (t < 240) {
    int loc = t / 40;
    int c = t - loc * 40;
    int node = nb + loc;
    if (node < NN) {
      float acc = bc[c];
#pragma unroll 8
      for (int k = 0; k < 128; k++) acc += shH[loc * 128 + k] * shW[k * 40 + c];
      out[(size_t)node * 40 + c] = acc;
    }
  }
}

// ============================ launch ============================

extern "C" void kernel_launch(void* const* d_in, const int* in_sizes, int n_in,
                              void* d_out, int out_size, void* d_ws, size_t ws_size,
                              hipStream_t stream) {
  const float* x   = (const float*)d_in[0];
  const int*   ei  = (const int*)d_in[1];
  const float* W1  = (const float*)d_in[2];
  const float* as1 = (const float*)d_in[3];
  const float* ad1 = (const float*)d_in[4];
  const float* b1  = (const float*)d_in[5];
  const float* W2  = (const float*)d_in[6];
  const float* as2 = (const float*)d_in[7];
  const float* ad2 = (const float*)d_in[8];
  const float* b2  = (const float*)d_in[9];
  const float* Wc  = (const float*)d_in[10];
  const float* bc  = (const float*)d_in[11];
  float* out = (float*)d_out;

  const int* esrc = ei;
  const int* edst = ei + NE;

  char* w = (char*)d_ws;
  auto alloc = [&](size_t bytes) {
    void* p = (void*)w;
    w += (bytes + 255) & ~(size_t)255;
    return p;
  };
  half_t* A   = (half_t*)alloc(sizeof(half_t) * (size_t)NN * 128);  // fp16 gather target
  float* B    = (float*)alloc(sizeof(float) * (size_t)NN * 128);    // fp32 layer output
  float* asrc = (float*)alloc(sizeof(float) * (size_t)NN * 4);
  float* adst = (float*)alloc(sizeof(float) * (size_t)NN * 4);
  int* deg    = (int*)alloc(sizeof(int) * NN);
  int* offs   = (int*)alloc(sizeof(int) * (NN + 1));
  int* cursor = (int*)alloc(sizeof(int) * NN);
  int* adj    = (int*)alloc(sizeof(int) * NE);
  int* bsum   = (int*)alloc(sizeof(int) * 256);

  // ---- CSR build (same graph both layers) ----
  k_zero<<<(NN + 255) / 256, 256, 0, stream>>>(deg, NN);
  k_count<<<(NE + 255) / 256, 256, 0, stream>>>(edst, deg);
  k_scan1<<<NB_SCAN, 256, 0, stream>>>(deg, offs, bsum);
  k_scan2<<<1, 256, 0, stream>>>(bsum, NB_SCAN);
  k_scan3<<<(NN + 255) / 256, 256, 0, stream>>>(offs, bsum, cursor);
  k_scatter<<<(NE + 255) / 256, 256, 0, stream>>>(esrc, edst, offs, cursor, adj);

  // ---- layer 1 ----
  k_gemm_att<<<(NN + 127) / 128, 256, 0, stream>>>(x, W1, as1, ad1, A, asrc, adst);
  k_aggregate<<<(NN + 3) / 4, 256, 0, stream>>>(A, offs, adj, asrc, adst, b1, B);

  // ---- layer 2 ----
  k_gemm_att<<<(NN + 127) / 128, 256, 0, stream>>>(B, W2, as2, ad2, A, asrc, adst);
  k_aggregate<<<(NN + 3) / 4, 256, 0, stream>>>(A, offs, adj, asrc, adst, b2, B);

  // ---- classifier ----
  k_classifier<<<(NN + 5) / 6, 256, 0, stream>>>(B, Wc, bc, out);
}

// Round 3
// 463.259 us; speedup vs baseline: 1.8147x; 1.4080x over previous
//
#include <hip/hip_runtime.h>

#define NN   100000
#define NE   1600000
#define BSH  9            // 512 nodes per bucket
#define BSZ  512
#define NBK  196          // ceil(NN/512)
#define TILE_A 8192
#define NBA  196          // ceil(NE/TILE_A)
#define TILE_H 4096
#define NBH  391          // ceil(NE/TILE_H)
#define CAPB 10240        // LDS staging capacity (entries) in k_binB

typedef _Float16 half_t;
typedef __attribute__((ext_vector_type(2))) _Float16 f16x2;
typedef __attribute__((ext_vector_type(4))) _Float16 f16x4;
typedef __attribute__((ext_vector_type(8))) _Float16 f16x8;
typedef __attribute__((ext_vector_type(4))) float    f32x4;

// ============================ small utils ============================

__global__ __launch_bounds__(256) void k_zero(int* __restrict__ p, int n) {
  int i = blockIdx.x * 256 + threadIdx.x;
  if (i < n) p[i] = 0;
}

// ============================ bucket histogram ============================
__global__ __launch_bounds__(256) void k_bhist(const int* __restrict__ dst, int* __restrict__ bcnt) {
  __shared__ int h[NBK];
  int t = threadIdx.x;
  for (int i = t; i < NBK; i += 256) h[i] = 0;
  __syncthreads();
  int e0 = blockIdx.x * TILE_H;
#pragma unroll
  for (int i = 0; i < TILE_H / 256; i++) {
    int e = e0 + t + i * 256;
    if (e < NE) atomicAdd(&h[dst[e] >> BSH], 1);
  }
  __syncthreads();
  for (int i = t; i < NBK; i += 256) {
    int c = h[i];
    if (c > 0) atomicAdd(&bcnt[i], c);
  }
}

// scan bucket counts -> bases & cursors; also set offs[NN]
__global__ __launch_bounds__(256) void k_bscan(const int* __restrict__ bcnt, int* __restrict__ bbase,
                                               int* __restrict__ bcur, int* __restrict__ offs) {
  __shared__ int sh[256];
  int t = threadIdx.x;
  int v = (t < NBK) ? bcnt[t] : 0;
  int x = v;
  sh[t] = x;
  for (int off = 1; off < 256; off <<= 1) {
    __syncthreads();
    int y = (t >= off) ? sh[t - off] : 0;
    __syncthreads();
    x += y;
    sh[t] = x;
  }
  if (t < NBK) {
    bbase[t] = x - v;
    bcur[t] = x - v;
  }
  if (t == 0) offs[NN] = NE;
}

// ============================ pass A: bin edges by bucket ============================
// per block: LDS counting sort of TILE_A edges by bucket, then contiguous flush per bucket.
__global__ __launch_bounds__(256) void k_binA(const int* __restrict__ src, const int* __restrict__ dst,
                                              int* __restrict__ bcur, unsigned int* __restrict__ bpk) {
  __shared__ int hist[NBK];
  __shared__ int hscan[NBK];
  __shared__ int gbase[NBK];
  __shared__ int cnt[NBK];
  __shared__ int ssc[256];
  __shared__ unsigned int staged[TILE_A];
  int t = threadIdx.x;
  int e0 = blockIdx.x * TILE_A;
  for (int i = t; i < NBK; i += 256) { hist[i] = 0; cnt[i] = 0; }
  __syncthreads();
  // histogram
#pragma unroll
  for (int i = 0; i < TILE_A / 256; i++) {
    int e = e0 + t + i * 256;
    if (e < NE) atomicAdd(&hist[dst[e] >> BSH], 1);
  }
  __syncthreads();
  // exclusive scan of hist (NBK <= 256)
  {
    int v = (t < NBK) ? hist[t] : 0;
    int x = v;
    ssc[t] = x;
    for (int off = 1; off < 256; off <<= 1) {
      __syncthreads();
      int y = (t >= off) ? ssc[t - off] : 0;
      __syncthreads();
      x += y;
      ssc[t] = x;
    }
    if (t < NBK) {
      hscan[t] = x - v;
      if (v > 0) gbase[t] = atomicAdd(&bcur[t], v);
    }
  }
  __syncthreads();
  // scatter into LDS staging (packed: src<<9 | dst&511)
#pragma unroll
  for (int i = 0; i < TILE_A / 256; i++) {
    int e = e0 + t + i * 256;
    if (e < NE) {
      int d = dst[e];
      int b = d >> BSH;
      int pos = hscan[b] + atomicAdd(&cnt[b], 1);
      staged[pos] = ((unsigned int)src[e] << BSH) | (unsigned int)(d & (BSZ - 1));
    }
  }
  __syncthreads();
  // contiguous flush, one bucket per wave round-robin
  int wave = t >> 6, lane = t & 63;
  for (int b = wave; b < NBK; b += 4) {
    int c = hist[b];
    if (c > 0) {
      int lo = hscan[b], gb = gbase[b];
      for (int j = lane; j < c; j += 64) bpk[gb + j] = staged[lo + j];
    }
  }
}

// ============================ pass B: sort bucket by dst, emit offs + adj ============================
__global__ __launch_bounds__(256) void k_binB(const unsigned int* __restrict__ bpk,
                                              const int* __restrict__ bbase,
                                              int* __restrict__ offs, int* __restrict__ adj) {
  __shared__ int lhist[BSZ];
  __shared__ int lscan[BSZ];
  __shared__ int lcur[BSZ];
  __shared__ int ssc[256];
  __shared__ unsigned int staged[CAPB];
  int b = blockIdx.x;
  int t = threadIdx.x;
  int nbeg = b << BSH;
  int nend = min(nbeg + BSZ, NN);
  int rbeg = bbase[b];
  int rend = (b + 1 < NBK) ? bbase[b + 1] : NE;
  int cnt = rend - rbeg;
  for (int i = t; i < BSZ; i += 256) { lhist[i] = 0; lcur[i] = 0; }
  __syncthreads();
  for (int i = t; i < cnt; i += 256) atomicAdd(&lhist[bpk[rbeg + i] & (BSZ - 1)], 1);
  __syncthreads();
  // exclusive scan of 512 with 256 threads (2 elems/thread)
  {
    int v0 = lhist[2 * t], v1 = lhist[2 * t + 1];
    int s2 = v0 + v1;
    int x = s2;
    ssc[t] = x;
    for (int off = 1; off < 256; off <<= 1) {
      __syncthreads();
      int y = (t >= off) ? ssc[t - off] : 0;
      __syncthreads();
      x += y;
      ssc[t] = x;
    }
    int ex = x - s2;
    lscan[2 * t] = ex;
    lscan[2 * t + 1] = ex + v0;
  }
  __syncthreads();
  // emit global CSR offsets for this bucket's nodes
  for (int i = t; i < nend - nbeg; i += 256) offs[nbeg + i] = rbeg + lscan[i];
  // scatter into LDS staging (sorted by dst)
  for (int i = t; i < cnt; i += 256) {
    unsigned int v = bpk[rbeg + i];
    int dl = v & (BSZ - 1);
    int idx = lscan[dl] + atomicAdd(&lcur[dl], 1);
    int s = (int)(v >> BSH);
    if (idx < CAPB) staged[idx] = (unsigned int)s;
    else adj[rbeg + idx] = s;  // overflow fallback (statistically never)
  }
  __syncthreads();
  // contiguous stream-out
  int lim = min(cnt, CAPB);
  for (int i = t; i < lim; i += 256) adj[rbeg + i] = (int)staged[i];
}

// ============================ MFMA GEMM + attention logits ============================
// H(fp16) = fp16(X) @ fp16(W); asrc/adst fp32 logits from the C-fragments.
// 256 thr = 4 waves; tile 128 rows x 128 cols; K-steps of 32.
// A-frag: lane holds A[m=lane&15][k=quad*8+j]; B-frag: B[k][n=lane&15] from [n][k] LDS.
// C-frag: col=lane&15, row=quad*4+reg.
template <typename T>
__global__ __launch_bounds__(256) void k_gemm_att(const T* __restrict__ X, const float* __restrict__ W,
                                                  const float* __restrict__ atts, const float* __restrict__ attd,
                                                  half_t* __restrict__ H, float* __restrict__ asrc,
                                                  float* __restrict__ adst) {
  __shared__ __align__(16) half_t Xt[128 * 40];   // [row][k], stride 40 halves
  __shared__ __align__(16) half_t Wt[128 * 40];   // [n][k], stride 40 halves
  int t = threadIdx.x;
  int wave = t >> 6, lane = t & 63;
  int l15 = lane & 15, quad = lane >> 4;
  int rb = blockIdx.x * 128;

  f32x4 acc[2][8];
#pragma unroll
  for (int rt = 0; rt < 2; rt++)
#pragma unroll
    for (int ct = 0; ct < 8; ct++) acc[rt][ct] = (f32x4){0.f, 0.f, 0.f, 0.f};

  for (int k0 = 0; k0 < 128; k0 += 32) {
    __syncthreads();
    // stage X tile: 128 rows x 32 k -> fp16
    if constexpr (sizeof(T) == 4) {
#pragma unroll
      for (int i = 0; i < 4; i++) {
        int lin = i * 256 + t;
        int row = lin >> 3;
        int c4 = (lin & 7) * 4;
        float4 v = make_float4(0.f, 0.f, 0.f, 0.f);
        int gr = rb + row;
        if (gr < NN) v = *(const float4*)((const float*)X + (size_t)gr * 128 + k0 + c4);
        f16x4 hv;
        hv[0] = (half_t)v.x; hv[1] = (half_t)v.y; hv[2] = (half_t)v.z; hv[3] = (half_t)v.w;
        *(f16x4*)(Xt + row * 40 + c4) = hv;
      }
    } else {
#pragma unroll
      for (int i = 0; i < 2; i++) {
        int lin = i * 256 + t;
        int row = lin >> 2;
        int c8 = (lin & 3) * 8;
        f16x8 hv = (f16x8)(half_t)0;
        int gr = rb + row;
        if (gr < NN) hv = *(const f16x8*)((const half_t*)X + (size_t)gr * 128 + k0 + c8);
        *(f16x8*)(Xt + row * 40 + c8) = hv;
      }
    }
    // stage W^T tile: W[k0+kr][n] -> Wt[n][kr]
#pragma unroll
    for (int i = 0; i < 4; i++) {
      int lin = i * 256 + t;
      int kr = lin >> 5;
      int n4 = (lin & 31) * 4;
      float4 v = *(const float4*)(W + (size_t)(k0 + kr) * 128 + n4);
      Wt[(n4 + 0) * 40 + kr] = (half_t)v.x;
      Wt[(n4 + 1) * 40 + kr] = (half_t)v.y;
      Wt[(n4 + 2) * 40 + kr] = (half_t)v.z;
      Wt[(n4 + 3) * 40 + kr] = (half_t)v.w;
    }
    __syncthreads();

    f16x8 a0 = *(const f16x8*)(Xt + (wave * 32 + l15) * 40 + quad * 8);
    f16x8 a1 = *(const f16x8*)(Xt + (wave * 32 + 16 + l15) * 40 + quad * 8);
#pragma unroll
    for (int ct = 0; ct < 8; ct++) {
      f16x8 b = *(const f16x8*)(Wt + (ct * 16 + l15) * 40 + quad * 8);
      acc[0][ct] = __builtin_amdgcn_mfma_f32_16x16x32_f16(a0, b, acc[0][ct], 0, 0, 0);
      acc[1][ct] = __builtin_amdgcn_mfma_f32_16x16x32_f16(a1, b, acc[1][ct], 0, 0, 0);
    }
  }

  // ---- store H as fp16 ----
#pragma unroll
  for (int rt = 0; rt < 2; rt++) {
    int rbase = rb + wave * 32 + rt * 16 + quad * 4;
#pragma unroll
    for (int reg = 0; reg < 4; reg++) {
      int row = rbase + reg;
      if (row < NN) {
#pragma unroll
        for (int ct = 0; ct < 8; ct++) {
          H[(size_t)row * 128 + ct * 16 + l15] = (half_t)acc[rt][ct][reg];
        }
      }
    }
  }

  // ---- attention logits ----
  float s_lo[4], s_hi[4], d_lo[4], d_hi[4];
#pragma unroll
  for (int h = 0; h < 4; h++) {
    s_lo[h] = atts[h * 32 + l15];
    s_hi[h] = atts[h * 32 + 16 + l15];
    d_lo[h] = attd[h * 32 + l15];
    d_hi[h] = attd[h * 32 + 16 + l15];
  }
#pragma unroll
  for (int rt = 0; rt < 2; rt++) {
    float ps[4][4], pd[4][4];  // [reg][head]
#pragma unroll
    for (int reg = 0; reg < 4; reg++)
#pragma unroll
      for (int h = 0; h < 4; h++) {
        ps[reg][h] = acc[rt][2 * h][reg] * s_lo[h] + acc[rt][2 * h + 1][reg] * s_hi[h];
        pd[reg][h] = acc[rt][2 * h][reg] * d_lo[h] + acc[rt][2 * h + 1][reg] * d_hi[h];
      }
#pragma unroll
    for (int m = 1; m < 16; m <<= 1) {
#pragma unroll
      for (int reg = 0; reg < 4; reg++)
#pragma unroll
        for (int h = 0; h < 4; h++) {
          ps[reg][h] += __shfl_xor(ps[reg][h], m, 64);
          pd[reg][h] += __shfl_xor(pd[reg][h], m, 64);
        }
    }
    float vs = 0.f, vd = 0.f;
#pragma unroll
    for (int reg = 0; reg < 4; reg++)
#pragma unroll
      for (int h = 0; h < 4; h++) {
        if (l15 == reg * 4 + h) { vs = ps[reg][h]; vd = pd[reg][h]; }
      }
    int row = rb + wave * 32 + rt * 16 + quad * 4 + (l15 >> 2);
    int h = l15 & 3;
    if (row < NN) {
      asrc[row * 4 + h] = vs;
      adst[row * 4 + h] = vd;
    }
  }
}

// ============================ per-node gather aggregation ============================
// one wave per dst node; 16 lanes x half8 per row; 4 edges in flight; fp16 output.
__global__ __launch_bounds__(256) void k_aggregate(const half_t* __restrict__ H, const int* __restrict__ offs,
                                                   const int* __restrict__ adj, const float* __restrict__ asrc,
                                                   const float* __restrict__ adst, const float* __restrict__ bias,
                                                   half_t* __restrict__ out) {
  int n = blockIdx.x * 4 + (threadIdx.x >> 6);
  if (n >= NN) return;
  int lane = threadIdx.x & 63;
  int l15 = lane & 15, g = lane >> 4;
  int head = l15 >> 2;
  float ad = adst[n * 4 + head];
  float acc[8] = {0.f, 0.f, 0.f, 0.f, 0.f, 0.f, 0.f, 0.f};
  float wsum = 0.f;
  int beg = offs[n], end = offs[n + 1];
  int i = beg + g;
  int s = (i < end) ? adj[i] : 0;
  while (i < end) {
    int inext = i + 4;
    int snext = (inext < end) ? adj[inext] : 0;   // prefetch: independent of this iter's chain
    float e = asrc[s * 4 + head] + ad;
    f16x8 hv = *(const f16x8*)(H + (size_t)s * 128 + l15 * 8);
    e = (e > 0.f) ? e : 0.2f * e;
    float w = __expf(e);
    wsum += w;
#pragma unroll
    for (int j = 0; j < 8; j++) acc[j] += w * (float)hv[j];
    s = snext;
    i = inext;
  }
  if (g == 0) {  // self loop
    float e = asrc[n * 4 + head] + ad;
    e = (e > 0.f) ? e : 0.2f * e;
    float w = __expf(e);
    wsum += w;
    f16x8 hv = *(const f16x8*)(H + (size_t)n * 128 + l15 * 8);
#pragma unroll
    for (int j = 0; j < 8; j++) acc[j] += w * (float)hv[j];
  }
#pragma unroll
  for (int m = 16; m < 64; m <<= 1) {
    wsum += __shfl_xor(wsum, m, 64);
#pragma unroll
    for (int j = 0; j < 8; j++) acc[j] += __shfl_xor(acc[j], m, 64);
  }
  float inv = 1.0f / (wsum + 1e-16f);
  float o0 = acc[0], o1 = acc[1];
  if (g == 1) { o0 = acc[2]; o1 = acc[3]; }
  if (g == 2) { o0 = acc[4]; o1 = acc[5]; }
  if (g == 3) { o0 = acc[6]; o1 = acc[7]; }
  int ch = l15 * 8 + g * 2;
  o0 = fmaxf(o0 * inv + bias[ch], 0.f);
  o1 = fmaxf(o1 * inv + bias[ch + 1], 0.f);
  f16x2 o;
  o[0] = (half_t)o0;
  o[1] = (half_t)o1;
  *(f16x2*)(out + (size_t)n * 128 + ch) = o;
}

// ============================ classifier (MFMA, N=40 padded to 48) ============================
__global__ __launch_bounds__(256) void k_classifier(const half_t* __restrict__ Hf, const float* __restrict__ Wc,
                                                    const float* __restrict__ bc, float* __restrict__ out) {
  __shared__ __align__(16) half_t Xt[128 * 40];   // [row][k], stride 40
  __shared__ __align__(16) half_t Wt[48 * 40];    // [n][k], stride 40
  int t = threadIdx.x;
  int wave = t >> 6, lane = t & 63;
  int l15 = lane & 15, quad = lane >> 4;
  int rb = blockIdx.x * 128;

  f32x4 acc[2][3];
#pragma unroll
  for (int rt = 0; rt < 2; rt++)
#pragma unroll
    for (int ct = 0; ct < 3; ct++) acc[rt][ct] = (f32x4){0.f, 0.f, 0.f, 0.f};

  for (int k0 = 0; k0 < 128; k0 += 32) {
    __syncthreads();
#pragma unroll
    for (int i = 0; i < 2; i++) {
      int lin = i * 256 + t;
      int row = lin >> 2;
      int c8 = (lin & 3) * 8;
      f16x8 hv = (f16x8)(half_t)0;
      int gr = rb + row;
      if (gr < NN) hv = *(const f16x8*)(Hf + (size_t)gr * 128 + k0 + c8);
      *(f16x8*)(Xt + row * 40 + c8) = hv;
    }
    // Wc[k][n] (n<40) -> Wt[n][kr], pad n=40..47 with 0
#pragma unroll
    for (int i = 0; i < 6; i++) {
      int lin = i * 256 + t;
      int kr = lin / 48;
      int n = lin - kr * 48;
      Wt[n * 40 + kr] = (n < 40) ? (half_t)Wc[(size_t)(k0 + kr) * 40 + n] : (half_t)0;
    }
    __syncthreads();

    f16x8 a0 = *(const f16x8*)(Xt + (wave * 32 + l15) * 40 + quad * 8);
    f16x8 a1 = *(const f16x8*)(Xt + (wave * 32 + 16 + l15) * 40 + quad * 8);
#pragma unroll
    for (int ct = 0; ct < 3; ct++) {
      f16x8 b = *(const f16x8*)(Wt + (ct * 16 + l15) * 40 + quad * 8);
      acc[0][ct] = __builtin_amdgcn_mfma_f32_16x16x32_f16(a0, b, acc[0][ct], 0, 0, 0);
      acc[1][ct] = __builtin_amdgcn_mfma_f32_16x16x32_f16(a1, b, acc[1][ct], 0, 0, 0);
    }
  }

#pragma unroll
  for (int rt = 0; rt < 2; rt++) {
#pragma unroll
    for (int ct = 0; ct < 3; ct++) {
      int col = ct * 16 + l15;
      if (col < 40) {
        float bv = bc[col];
#pragma unroll
        for (int reg = 0; reg < 4; reg++) {
          int row = rb + wave * 32 + rt * 16 + quad * 4 + reg;
          if (row < NN) out[(size_t)row * 40 + col] = acc[rt][ct][reg] + bv;
        }
      }
    }
  }
}

// ============================ launch ============================

extern "C" void kernel_launch(void* const* d_in, const int* in_sizes, int n_in,
                              void* d_out, int out_size, void* d_ws, size_t ws_size,
                              hipStream_t stream) {
  const float* x   = (const float*)d_in[0];
  const int*   ei  = (const int*)d_in[1];
  const float* W1  = (const float*)d_in[2];
  const float* as1 = (const float*)d_in[3];
  const float* ad1 = (const float*)d_in[4];
  const float* b1  = (const float*)d_in[5];
  const float* W2  = (const float*)d_in[6];
  const float* as2 = (const float*)d_in[7];
  const float* ad2 = (const float*)d_in[8];
  const float* b2  = (const float*)d_in[9];
  const float* Wc  = (const float*)d_in[10];
  const float* bc  = (const float*)d_in[11];
  float* out = (float*)d_out;

  const int* esrc = ei;
  const int* edst = ei + NE;

  char* w = (char*)d_ws;
  auto alloc = [&](size_t bytes) {
    void* p = (void*)w;
    w += (bytes + 255) & ~(size_t)255;
    return p;
  };
  half_t* A   = (half_t*)alloc(sizeof(half_t) * (size_t)NN * 128);  // gather target
  half_t* B   = (half_t*)alloc(sizeof(half_t) * (size_t)NN * 128);  // layer output
  float* asrc = (float*)alloc(sizeof(float) * (size_t)NN * 4);
  float* adst = (float*)alloc(sizeof(float) * (size_t)NN * 4);
  int* offs   = (int*)alloc(sizeof(int) * (NN + 1));
  int* adj    = (int*)alloc(sizeof(int) * NE);
  unsigned int* bpk = (unsigned int*)alloc(sizeof(unsigned int) * NE);
  int* bcnt   = (int*)alloc(sizeof(int) * NBK);
  int* bbase  = (int*)alloc(sizeof(int) * NBK);
  int* bcur   = (int*)alloc(sizeof(int) * NBK);

  // ---- CSR build via two-pass LDS counting sort ----
  k_zero<<<1, 256, 0, stream>>>(bcnt, NBK);
  k_bhist<<<NBH, 256, 0, stream>>>(edst, bcnt);
  k_bscan<<<1, 256, 0, stream>>>(bcnt, bbase, bcur, offs);
  k_binA<<<NBA, 256, 0, stream>>>(esrc, edst, bcur, bpk);
  k_binB<<<NBK, 256, 0, stream>>>(bpk, bbase, offs, adj);

  // ---- layer 1 ----
  k_gemm_att<float><<<(NN + 127) / 128, 256, 0, stream>>>(x, W1, as1, ad1, A, asrc, adst);
  k_aggregate<<<(NN + 3) / 4, 256, 0, stream>>>(A, offs, adj, asrc, adst, b1, B);

  // ---- layer 2 ----
  k_gemm_att<half_t><<<(NN + 127) / 128, 256, 0, stream>>>(B, W2, as2, ad2, A, asrc, adst);
  k_aggregate<<<(NN + 3) / 4, 256, 0, stream>>>(A, offs, adj, asrc, adst, b2, B);

  // ---- classifier ----
  k_classifier<<<(NN + 127) / 128, 256, 0, stream>>>(B, Wc, bc, out);
}